// Round 7
// baseline (1712.267 us; speedup 1.0000x reference)
//
#include <hip/hip_runtime.h>
#include <math.h>

#define BATCH   4
#define SEQ     2048
#define DMODEL  768
#define DSTATE  16
#define DCONV   4
#define HEADDIM 64
#define DINNER  1536
#define NHEADS  24
#define CONVDIM 1568
#define DINPROJ 3128
#define DFFN    3072
#define ROWS    (BATCH*SEQ)   // 8192
#define QCH     128           // scan chunk length
#define NCHUNK  (SEQ/QCH)     // 16

typedef __attribute__((ext_vector_type(8))) short bhalf8;   // 8 bf16 (4 VGPRs)
typedef __attribute__((ext_vector_type(4))) float floatx4;  // 4 fp32 acc

__device__ __forceinline__ float gelu_f(float x) {
    return 0.5f * x * (1.0f + erff(x * 0.70710678118654752f));
}

// RNE split: v ~= hi + lo (bf16 each), both rounded-to-nearest-even
__device__ __forceinline__ void splitRNE(float v, unsigned short& h, unsigned short& l) {
    unsigned u = __float_as_uint(v);
    unsigned rr = u + 0x7FFFu + ((u >> 16) & 1u);
    unsigned short hi = (unsigned short)(rr >> 16);
    float rem = v - __uint_as_float(((unsigned)hi) << 16);
    unsigned u2 = __float_as_uint(rem);
    unsigned r2 = u2 + 0x7FFFu + ((u2 >> 16) & 1u);
    h = hi;
    l = (unsigned short)(r2 >> 16);
}

// async global->LDS DMA, 16B per lane (dest = wave-uniform base + lane*16)
__device__ __forceinline__ void gl16(const unsigned short* g, unsigned short* l) {
    __builtin_amdgcn_global_load_lds(
        (const __attribute__((address_space(1))) void*)g,
        (__attribute__((address_space(3))) void*)l, 16, 0, 0);
}

// ---------------- block reduction (256 threads, wave64) ----------------
__device__ __forceinline__ float2 blockReduce2(float a, float b) {
    #pragma unroll
    for (int o = 32; o > 0; o >>= 1) {
        a += __shfl_down(a, o, 64);
        b += __shfl_down(b, o, 64);
    }
    __shared__ float sa[4], sb[4];
    int w = threadIdx.x >> 6, lane = threadIdx.x & 63;
    if (lane == 0) { sa[w] = a; sb[w] = b; }
    __syncthreads();
    if (threadIdx.x == 0) {
        int nw = blockDim.x >> 6;
        for (int i = 1; i < nw; ++i) { a += sa[i]; b += sb[i]; }
        sa[0] = a; sb[0] = b;
    }
    __syncthreads();
    return make_float2(sa[0], sb[0]);
}

// ---------------- LayerNorm, fp32 out (final, with residual) -------------
__global__ __launch_bounds__(256) void ln_kernel(
    const float* __restrict__ x, const float* __restrict__ res,
    const float* __restrict__ w, const float* __restrict__ b,
    float* __restrict__ out)
{
    int r = blockIdx.x;
    const float* xr = x + (size_t)r * DMODEL;
    float v[3]; float s = 0.f, ss = 0.f;
    #pragma unroll
    for (int i = 0; i < 3; ++i) {
        int c = threadIdx.x + i * 256;
        float t = xr[c];
        if (res) t += res[(size_t)r * DMODEL + c];
        v[i] = t; s += t; ss += t * t;
    }
    float2 red = blockReduce2(s, ss);
    float mean = red.x * (1.0f / DMODEL);
    float var  = red.y * (1.0f / DMODEL) - mean * mean;
    float inv  = rsqrtf(var + 1e-5f);
    #pragma unroll
    for (int i = 0; i < 3; ++i) {
        int c = threadIdx.x + i * 256;
        out[(size_t)r * DMODEL + c] = (v[i] - mean) * inv * w[c] + b[c];
    }
}

// ---------------- LayerNorm, bf16 hi/lo plane out (xn for in_proj) -------
__global__ __launch_bounds__(256) void ln_split_kernel(
    const float* __restrict__ x,
    const float* __restrict__ w, const float* __restrict__ b,
    unsigned short* __restrict__ H, unsigned short* __restrict__ L)
{
    int r = blockIdx.x;
    const float* xr = x + (size_t)r * DMODEL;
    float v[3]; float s = 0.f, ss = 0.f;
    #pragma unroll
    for (int i = 0; i < 3; ++i) {
        int c = threadIdx.x + i * 256;
        float t = xr[c];
        v[i] = t; s += t; ss += t * t;
    }
    float2 red = blockReduce2(s, ss);
    float mean = red.x * (1.0f / DMODEL);
    float var  = red.y * (1.0f / DMODEL) - mean * mean;
    float inv  = rsqrtf(var + 1e-5f);
    #pragma unroll
    for (int i = 0; i < 3; ++i) {
        int c = threadIdx.x + i * 256;
        float o = (v[i] - mean) * inv * w[c] + b[c];
        unsigned short h, l;
        splitRNE(o, h, l);
        H[(size_t)r * DMODEL + c] = h;
        L[(size_t)r * DMODEL + c] = l;
    }
}

// ---------------- weight transpose + bf16 hi/lo split ---------------------
__global__ __launch_bounds__(256) void wconv(
    const float* __restrict__ W, unsigned short* __restrict__ TH,
    unsigned short* __restrict__ TL, int K, int N)
{
    __shared__ float t[32][33];
    int tx = threadIdx.x & 31, ty = threadIdx.x >> 5;  // ty 0..7
    int kb = blockIdx.y * 32, nb = blockIdx.x * 32;
    #pragma unroll
    for (int i = 0; i < 4; ++i) {
        int k = kb + ty + i * 8, n = nb + tx;
        t[ty + i * 8][tx] = (k < K && n < N) ? W[(size_t)k * N + n] : 0.f;
    }
    __syncthreads();
    #pragma unroll
    for (int i = 0; i < 4; ++i) {
        int n = nb + ty + i * 8, k = kb + tx;
        if (n < N && k < K) {
            unsigned short hi, lo;
            splitRNE(t[tx][ty + i * 8], hi, lo);
            TH[(size_t)n * K + k] = hi;
            TL[(size_t)n * K + k] = lo;
        }
    }
}

// ---------------- bf16x3 split-GEMM via MFMA (r1 proven structure) --------
// Single 32 KB staging buffer, 2 barriers/k-tile, stage(kt+1) issued after
// the second barrier so DMA latency hides under the MFMA cluster. 5 blocks/
// CU (LDS-capped) provides the cross-block overlap that covers the drains.
// Used for the big-grid shapes (in_proj, ffn1).
__global__ __launch_bounds__(256) void gemm3(
    const unsigned short* __restrict__ AHg, const unsigned short* __restrict__ ALg,
    const unsigned short* __restrict__ BHg, const unsigned short* __restrict__ BLg,
    float* __restrict__ C, unsigned short* __restrict__ CHo, unsigned short* __restrict__ CLo,
    const float* __restrict__ bias,
    int M, int N, int K, int ldc, int coloff,
    int revA, int revC, int act)
{
    (void)M;
    __shared__ __align__(16) unsigned short AsH[128 * 32], AsL[128 * 32];
    __shared__ __align__(16) unsigned short BsH[128 * 32], BsL[128 * 32];

    const int tid = threadIdx.x;
    const int m0 = blockIdx.y * 128;
    const int n0 = blockIdx.x * 128;

    size_t aoff[2], boff[2];
    int lofs[2];
    #pragma unroll
    for (int q = 0; q < 2; ++q) {
        int row = (tid >> 2) + 64 * q;
        int sd  = (tid & 3) ^ ((row >> 1) & 3);   // inverse-swizzled data slot
        int ar = m0 + row;
        if (revA) ar = (ar & ~(SEQ - 1)) + (SEQ - 1 - (ar & (SEQ - 1)));
        aoff[q] = (size_t)ar * K + sd * 8;
        boff[q] = (size_t)(n0 + row) * K + sd * 8;
        lofs[q] = (tid + 256 * q) * 8;
    }

    auto stage = [&](int k0) {
        #pragma unroll
        for (int q = 0; q < 2; ++q) {
            gl16(AHg + aoff[q] + k0, AsH + lofs[q]);
            gl16(ALg + aoff[q] + k0, AsL + lofs[q]);
            gl16(BHg + boff[q] + k0, BsH + lofs[q]);
            gl16(BLg + boff[q] + k0, BsL + lofs[q]);
        }
    };

    auto frag = [&](const unsigned short* buf, int row, int slot) -> bhalf8 {
        int sp = slot ^ ((row >> 1) & 3);
        return *(const bhalf8*)(buf + row * 32 + sp * 8);
    };

    const int w = tid >> 6, lane = tid & 63;
    const int rw = (w >> 1) * 64, cw = (w & 1) * 64;
    const int lr = lane & 15;
    const int lq = lane >> 4;

    floatx4 acc[4][4];
    const floatx4 fz = {0.f, 0.f, 0.f, 0.f};
    #pragma unroll
    for (int i = 0; i < 4; ++i)
        #pragma unroll
        for (int j = 0; j < 4; ++j) acc[i][j] = fz;

    const int ktiles = K >> 5;
    stage(0);
    for (int kt = 0; kt < ktiles; ++kt) {
        __syncthreads();                     // drains vmcnt(0): tile visible
        bhalf8 ah[4], al[4], bh[4], bl[4];
        #pragma unroll
        for (int i = 0; i < 4; ++i) {
            int ra = rw + i * 16 + lr;
            int rb = cw + i * 16 + lr;
            ah[i] = frag(AsH, ra, lq);
            al[i] = frag(AsL, ra, lq);
            bh[i] = frag(BsH, rb, lq);
            bl[i] = frag(BsL, rb, lq);
        }
        __syncthreads();                     // all lanes' ds_reads retired
        if (kt + 1 < ktiles) stage((kt + 1) * 32);  // DMA overlaps MFMAs below
        #pragma unroll
        for (int i = 0; i < 4; ++i)
            #pragma unroll
            for (int j = 0; j < 4; ++j) {
                acc[i][j] = __builtin_amdgcn_mfma_f32_16x16x32_bf16(ah[i], bh[j], acc[i][j], 0, 0, 0);
                acc[i][j] = __builtin_amdgcn_mfma_f32_16x16x32_bf16(ah[i], bl[j], acc[i][j], 0, 0, 0);
                acc[i][j] = __builtin_amdgcn_mfma_f32_16x16x32_bf16(al[i], bh[j], acc[i][j], 0, 0, 0);
            }
    }

    #pragma unroll
    for (int i = 0; i < 4; ++i) {
        #pragma unroll
        for (int j = 0; j < 4; ++j) {
            int gc = n0 + cw + j * 16 + lr;
            if (gc < N) {
                float bv = bias ? bias[gc] : 0.f;
                #pragma unroll
                for (int rg = 0; rg < 4; ++rg) {
                    int gm = m0 + rw + i * 16 + lq * 4 + rg;
                    if (revC) gm = (gm & ~(SEQ - 1)) + (SEQ - 1 - (gm & (SEQ - 1)));
                    float v = acc[i][j][rg] + bv;
                    if (act) v = gelu_f(v);
                    size_t o = (size_t)gm * ldc + coloff + gc;
                    if (CHo) {
                        unsigned short h, l;
                        splitRNE(v, h, l);
                        CHo[o] = h; CLo[o] = l;
                    } else {
                        C[o] = v;
                    }
                }
            }
        }
    }
}

// ---------------- bf16x3 split-GEMM, 64x64 SINGLE-WAVE (small-N shapes) ---
// Fixes grid starvation for out_proj/ffn2 (N=768: 384 blocks at 128-tile =
// 30% machine fill -> 1536 blocks at 64-tile = full fill). One wave/block:
// NO barriers — per-wave vmcnt/lgkmcnt ordering only; 16 KB LDS -> 10
// blocks/CU, fully independent waves hide each other's DMA drains.
__global__ __launch_bounds__(64) void gemm1w(
    const unsigned short* __restrict__ AHg, const unsigned short* __restrict__ ALg,
    const unsigned short* __restrict__ BHg, const unsigned short* __restrict__ BLg,
    float* __restrict__ C, unsigned short* __restrict__ CHo, unsigned short* __restrict__ CLo,
    const float* __restrict__ bias,
    int M, int N, int K, int ldc, int coloff,
    int revA, int revC, int act)
{
    (void)M;
    __shared__ __align__(16) unsigned short AsH[64 * 32], AsL[64 * 32];
    __shared__ __align__(16) unsigned short BsH[64 * 32], BsL[64 * 32];

    const int tid = threadIdx.x;          // 0..63 (one wave)
    const int m0 = blockIdx.y * 64;
    const int n0 = blockIdx.x * 64;

    // staging: 4 chunks of 16 rows per plane; lane handles row (tid>>2)+16q,
    // slot (tid&3) with the same XOR swizzle as gemm3 (src-swizzled, linear LDS)
    size_t aoff[4], boff[4];
    int lofs[4];
    #pragma unroll
    for (int q = 0; q < 4; ++q) {
        int row = (tid >> 2) + 16 * q;
        int sd  = (tid & 3) ^ ((row >> 1) & 3);
        int ar = m0 + row;
        if (revA) ar = (ar & ~(SEQ - 1)) + (SEQ - 1 - (ar & (SEQ - 1)));
        aoff[q] = (size_t)ar * K + sd * 8;
        boff[q] = (size_t)(n0 + row) * K + sd * 8;
        lofs[q] = (tid + 64 * q) * 8;
    }

    auto stage = [&](int k0) {
        #pragma unroll
        for (int q = 0; q < 4; ++q) {
            gl16(AHg + aoff[q] + k0, AsH + lofs[q]);
            gl16(ALg + aoff[q] + k0, AsL + lofs[q]);
            gl16(BHg + boff[q] + k0, BsH + lofs[q]);
            gl16(BLg + boff[q] + k0, BsL + lofs[q]);
        }
    };

    auto frag = [&](const unsigned short* buf, int row, int slot) -> bhalf8 {
        int sp = slot ^ ((row >> 1) & 3);
        return *(const bhalf8*)(buf + row * 32 + sp * 8);
    };

    const int lr = tid & 15;
    const int lq = tid >> 4;

    floatx4 acc[4][4];
    const floatx4 fz = {0.f, 0.f, 0.f, 0.f};
    #pragma unroll
    for (int i = 0; i < 4; ++i)
        #pragma unroll
        for (int j = 0; j < 4; ++j) acc[i][j] = fz;

    const int ktiles = K >> 5;
    stage(0);
    for (int kt = 0; kt < ktiles; ++kt) {
        asm volatile("s_waitcnt vmcnt(0)" ::: "memory");   // tile kt in LDS
        bhalf8 ah[4], al[4], bh[4], bl[4];
        #pragma unroll
        for (int i = 0; i < 4; ++i) {
            int rr = i * 16 + lr;
            ah[i] = frag(AsH, rr, lq);
            al[i] = frag(AsL, rr, lq);
            bh[i] = frag(BsH, rr, lq);
            bl[i] = frag(BsL, rr, lq);
        }
        // frags in flight; drain DS before next DMA overwrites the buffer
        asm volatile("s_waitcnt lgkmcnt(0)" ::: "memory");
        if (kt + 1 < ktiles) stage((kt + 1) * 32);   // DMA overlaps MFMAs
        #pragma unroll
        for (int i = 0; i < 4; ++i)
            #pragma unroll
            for (int j = 0; j < 4; ++j) {
                acc[i][j] = __builtin_amdgcn_mfma_f32_16x16x32_bf16(ah[i], bh[j], acc[i][j], 0, 0, 0);
                acc[i][j] = __builtin_amdgcn_mfma_f32_16x16x32_bf16(ah[i], bl[j], acc[i][j], 0, 0, 0);
                acc[i][j] = __builtin_amdgcn_mfma_f32_16x16x32_bf16(al[i], bh[j], acc[i][j], 0, 0, 0);
            }
    }

    #pragma unroll
    for (int i = 0; i < 4; ++i) {
        #pragma unroll
        for (int j = 0; j < 4; ++j) {
            int gc = n0 + j * 16 + lr;
            if (gc < N) {
                float bv = bias ? bias[gc] : 0.f;
                #pragma unroll
                for (int rg = 0; rg < 4; ++rg) {
                    int gm = m0 + i * 16 + lq * 4 + rg;
                    if (revC) gm = (gm & ~(SEQ - 1)) + (SEQ - 1 - (gm & (SEQ - 1)));
                    float v = acc[i][j][rg] + bv;
                    if (act) v = gelu_f(v);
                    size_t o = (size_t)gm * ldc + coloff + gc;
                    if (CHo) {
                        unsigned short h, l;
                        splitRNE(v, h, l);
                        CHo[o] = h; CLo[o] = l;
                    } else {
                        C[o] = v;
                    }
                }
            }
        }
    }
}

// ---------------- depthwise causal conv + SiLU (float4) + fused dt/dA -----
__global__ __launch_bounds__(256) void conv_kernel(
    const float* __restrict__ zx, const float* __restrict__ cw,
    const float* __restrict__ cb, float* __restrict__ xcv,
    float* __restrict__ bc,
    const float* __restrict__ dt_bias, const float* __restrict__ A_log,
    float* __restrict__ dtda)
{
    int cg = blockIdx.x * 256 + threadIdx.x;   // channel group of 4
    int r = blockIdx.y;
    if (cg < CONVDIM / 4) {
        int c = cg * 4;
        int t = r & (SEQ - 1);
        int rb = r & ~(SEQ - 1);
        float4 acc = *(const float4*)&cb[c];
        #pragma unroll
        for (int k = 0; k < DCONV; ++k) {
            int tt = t - (DCONV - 1) + k;
            if (tt >= 0) {
                float4 xv = *(const float4*)&zx[(size_t)(rb + tt) * DINPROJ + DINNER + c];
                acc.x += cw[(c + 0) * DCONV + k] * xv.x;
                acc.y += cw[(c + 1) * DCONV + k] * xv.y;
                acc.z += cw[(c + 2) * DCONV + k] * xv.z;
                acc.w += cw[(c + 3) * DCONV + k] * xv.w;
            }
        }
        float4 v;
        v.x = acc.x / (1.0f + expf(-acc.x));
        v.y = acc.y / (1.0f + expf(-acc.y));
        v.z = acc.z / (1.0f + expf(-acc.z));
        v.w = acc.w / (1.0f + expf(-acc.w));
        if (c < DINNER) *(float4*)&xcv[(size_t)r * DINNER + c] = v;
        else            *(float4*)&bc[(size_t)r * 32 + (c - DINNER)] = v;
    } else if (cg >= CONVDIM / 4 && cg < CONVDIM / 4 + NHEADS / 4) {
        int h0 = (cg - CONVDIM / 4) * 4;
        float4 zv = *(const float4*)&zx[(size_t)r * DINPROJ + (DINPROJ - NHEADS) + h0];
        float zz[4] = {zv.x, zv.y, zv.z, zv.w};
        #pragma unroll
        for (int j = 0; j < 4; ++j) {
            int h = h0 + j;
            float v = zz[j] + dt_bias[h];
            float dt = (v > 20.f) ? v : log1pf(expf(v));
            float A = -expf(A_log[h]);
            float2 o = make_float2(dt, expf(dt * A));
            *(float2*)&dtda[(size_t)r * 48 + 2 * h] = o;
        }
    }
}

// ---------------- chunked scan, phase A: per-chunk local scan -------------
__global__ __launch_bounds__(64) void scan_a(
    const float* __restrict__ xcv, const float* __restrict__ bc,
    const float* __restrict__ dtda, const float* __restrict__ Dp,
    float* __restrict__ yout, float* __restrict__ S, float* __restrict__ cd)
{
    int blk = blockIdx.x;
    int bh = blk / NCHUNK, c = blk - bh * NCHUNK;
    int b = bh / NHEADS, h = bh - b * NHEADS;
    int p = threadIdx.x;
    float hs[DSTATE] = {};
    float Dv = Dp[h];
    float cum = 1.f;
    int t0 = c * QCH;
    for (int t = t0; t < t0 + QCH; ++t) {
        size_t r = (size_t)b * SEQ + t;
        float2 dd = *(const float2*)&dtda[r * 48 + 2 * h];
        float dt = dd.x;
        float dA = dd.y;
        float x  = xcv[r * DINNER + h * HEADDIM + p];
        cum *= dA;
        float coef = dt * x;
        const float* bcr = bc + r * 32;
        float y = 0.f;
        #pragma unroll
        for (int n = 0; n < DSTATE; ++n) {
            hs[n] = hs[n] * dA + coef * bcr[n];
            y += hs[n] * bcr[16 + n];
        }
        yout[r * DINPROJ + DINNER + h * HEADDIM + p] = y + Dv * x;
        if (p == 0) cd[r * NHEADS + h] = cum;
    }
    float* Sp = S + (((size_t)bh * NCHUNK + c) * HEADDIM + p) * DSTATE;
    #pragma unroll
    for (int n = 0; n < DSTATE; ++n) Sp[n] = hs[n];
}

// ---------------- chunked scan, phase B: sequential chunk combine ---------
__global__ __launch_bounds__(64) void scan_b(
    const float* __restrict__ cd, float* __restrict__ S)
{
    int bh = blockIdx.x;
    int b = bh / NHEADS, h = bh - b * NHEADS;
    int p = threadIdx.x;
    float H[DSTATE] = {};
    for (int c = 0; c < NCHUNK; ++c) {
        float* Sp = S + (((size_t)bh * NCHUNK + c) * HEADDIM + p) * DSTATE;
        float P = cd[((size_t)b * SEQ + c * QCH + QCH - 1) * NHEADS + h];
        float s[DSTATE];
        #pragma unroll
        for (int n = 0; n < DSTATE; ++n) s[n] = Sp[n];
        #pragma unroll
        for (int n = 0; n < DSTATE; ++n) Sp[n] = H[n];
        #pragma unroll
        for (int n = 0; n < DSTATE; ++n) H[n] = P * H[n] + s[n];
    }
}

// ---------------- chunked scan, phase C: carry correction -----------------
__global__ __launch_bounds__(64) void scan_c(
    const float* __restrict__ bc, const float* __restrict__ cd,
    const float* __restrict__ S, float* __restrict__ yout)
{
    int blk = blockIdx.x;
    int bh = blk / (NCHUNK - 1), c = blk - bh * (NCHUNK - 1) + 1;
    int b = bh / NHEADS, h = bh - b * NHEADS;
    int p = threadIdx.x;
    const float* Hp = S + (((size_t)bh * NCHUNK + c) * HEADDIM + p) * DSTATE;
    float H[DSTATE];
    #pragma unroll
    for (int n = 0; n < DSTATE; ++n) H[n] = Hp[n];
    int t0 = c * QCH;
    for (int t = t0; t < t0 + QCH; ++t) {
        size_t r = (size_t)b * SEQ + t;
        const float* Cr = bc + r * 32 + 16;
        float dot = 0.f;
        #pragma unroll
        for (int n = 0; n < DSTATE; ++n) dot += H[n] * Cr[n];
        float cum = cd[r * NHEADS + h];
        yout[r * DINPROJ + DINNER + h * HEADDIM + p] += cum * dot;
    }
}

// ---------------- gated RMSNorm -> bf16 hi/lo planes ----------------------
__global__ __launch_bounds__(256) void gnorm_kernel(
    const float* __restrict__ zx, const float* __restrict__ nw,
    unsigned short* __restrict__ H, unsigned short* __restrict__ L)
{
    int r = blockIdx.x;
    const float* zr = zx + (size_t)r * DINPROJ;
    float v[6]; float ss = 0.f;
    #pragma unroll
    for (int i = 0; i < 6; ++i) {
        int c = threadIdx.x + i * 256;
        float z = zr[c];
        float y = zr[DINNER + c];
        float t = y * z / (1.0f + expf(-z));
        v[i] = t; ss += t * t;
    }
    float2 red = blockReduce2(ss, 0.f);
    float sc = rsqrtf(red.x * (1.0f / DINNER) + 1e-5f);
    #pragma unroll
    for (int i = 0; i < 6; ++i) {
        int c = threadIdx.x + i * 256;
        float o = v[i] * sc * nw[c];
        unsigned short h, l;
        splitRNE(o, h, l);
        H[(size_t)r * DINNER + c] = h;
        L[(size_t)r * DINNER + c] = l;
    }
}

extern "C" void kernel_launch(void* const* d_in, const int* in_sizes, int n_in,
                              void* d_out, int out_size, void* d_ws, size_t ws_size,
                              hipStream_t stream)
{
    (void)in_sizes; (void)n_in; (void)out_size; (void)ws_size;
    const float* x     = (const float*)d_in[0];
    const float* ln1w  = (const float*)d_in[1];
    const float* ln1b  = (const float*)d_in[2];
    const float* ln2w  = (const float*)d_in[3];
    const float* ln2b  = (const float*)d_in[4];
    const float* ffnw1 = (const float*)d_in[5];
    const float* ffnb1 = (const float*)d_in[6];
    const float* ffnw2 = (const float*)d_in[7];
    const float* ffnb2 = (const float*)d_in[8];
    const float* p[2][8];
    for (int d = 0; d < 2; ++d)
        for (int i = 0; i < 8; ++i)
            p[d][i] = (const float*)d_in[9 + d * 8 + i];

    float* ws   = (float*)d_ws;
    float* zx   = ws;
    float* bi   = zx + (size_t)ROWS * DINPROJ;
    float* S    = bi + (size_t)ROWS * DINNER;
    float* Wbuf = S  + (size_t)ROWS * DINNER;
    float* bcb  = Wbuf + 2402304;
    float* dtda = bcb + (size_t)ROWS * 32;
    float* Sbuf = Wbuf;                       // alias (dead in_proj weights)
    float* cdbf = Wbuf + (size_t)BATCH * NHEADS * NCHUNK * HEADDIM * DSTATE;

    unsigned short* xnH = (unsigned short*)d_out;              // xn planes in d_out
    unsigned short* xnL = xnH + (size_t)ROWS * DMODEL;
    float* xcv = S;
    unsigned short* znH = (unsigned short*)S;                  // zn planes (xcv dead)
    unsigned short* znL = znH + (size_t)ROWS * DINNER;
    unsigned short* biH = (unsigned short*)bi;
    unsigned short* biL = biH + (size_t)ROWS * DINNER;
    unsigned short* hmH = (unsigned short*)zx;                 // hmid planes (zx dead)
    unsigned short* hmL = hmH + (size_t)ROWS * DFFN;
    float* ffo = S + 4718592;   // after ffn weight-plane region (18.9 MB)

    // 1. ln1: x -> xn bf16 hi/lo planes (in d_out)
    ln_split_kernel<<<ROWS, 256, 0, stream>>>(x, ln1w, ln1b, xnH, xnL);

    for (int d = 0; d < 2; ++d) {
        unsigned short* WH = (unsigned short*)Wbuf;
        unsigned short* WL = WH + (size_t)DINPROJ * DMODEL;
        wconv<<<dim3((DINPROJ + 31) / 32, DMODEL / 32), 256, 0, stream>>>(
            p[d][0], WH, WL, DMODEL, DINPROJ);
        // 2. in_proj: zx = xn(flip if d==1) @ in_w   [8192 x 3128] fp32 out
        gemm3<<<dim3((DINPROJ + 127) / 128, ROWS / 128), 256, 0, stream>>>(
            xnH, xnL, WH, WL, zx, nullptr, nullptr, nullptr,
            ROWS, DINPROJ, DMODEL, DINPROJ, 0, d, 0, 0);
        // 3. conv + silu -> xcv, bcb; fused dt/dA -> dtda
        conv_kernel<<<dim3(2, ROWS), 256, 0, stream>>>(
            zx, p[d][1], p[d][2], xcv, bcb, p[d][3], p[d][4], dtda);
        // 4. chunked scan -> y (+D*x) into zx cols [1536,3072)
        scan_a<<<BATCH * NHEADS * NCHUNK, 64, 0, stream>>>(
            xcv, bcb, dtda, p[d][5], zx, Sbuf, cdbf);
        scan_b<<<BATCH * NHEADS, 64, 0, stream>>>(cdbf, Sbuf);
        scan_c<<<BATCH * NHEADS * (NCHUNK - 1), 64, 0, stream>>>(
            bcb, cdbf, Sbuf, zx);
        // 5. gated RMSNorm -> zn bf16 planes (xcv dead)
        gnorm_kernel<<<ROWS, 256, 0, stream>>>(zx, p[d][6], znH, znL);
        // 6. out_proj: bi planes[:, d*768:(d+1)*768] = zn @ out_w, flip if d==1
        //    small-N shape -> 64x64 single-wave kernel (full machine fill)
        unsigned short* WL2 = WH + (size_t)DMODEL * DINNER;
        wconv<<<dim3(DMODEL / 32, DINNER / 32), 256, 0, stream>>>(
            p[d][7], WH, WL2, DINNER, DMODEL);
        gemm1w<<<dim3(DMODEL / 64, ROWS / 64), 64, 0, stream>>>(
            znH, znL, WH, WL2, nullptr, biH, biL, nullptr,
            ROWS, DMODEL, DINNER, DINNER, d * DMODEL, 0, d, 0);
    }

    // 7. ffn1: hmid planes = split(gelu(bi @ w1 + b1))  [8192 x 3072]
    {
        unsigned short* WH = (unsigned short*)S;
        unsigned short* WL = WH + (size_t)DFFN * DINNER;
        wconv<<<dim3(DFFN / 32, DINNER / 32), 256, 0, stream>>>(
            ffnw1, WH, WL, DINNER, DFFN);
        gemm3<<<dim3(DFFN / 128, ROWS / 128), 256, 0, stream>>>(
            biH, biL, WH, WL, nullptr, hmH, hmL, ffnb1,
            ROWS, DFFN, DINNER, DFFN, 0, 0, 0, 1);
    }
    // 8. ffn2: ffo = gelu(hmid @ w2 + b2) [8192 x 768] fp32
    //    small-N shape -> 64x64 single-wave kernel
    {
        unsigned short* WH = (unsigned short*)S;
        unsigned short* WL = WH + (size_t)DMODEL * DFFN;
        wconv<<<dim3(DMODEL / 32, DFFN / 32), 256, 0, stream>>>(
            ffnw2, WH, WL, DFFN, DMODEL);
        gemm1w<<<dim3(DMODEL / 64, ROWS / 64), 64, 0, stream>>>(
            hmH, hmL, WH, WL, ffo, nullptr, nullptr, ffnb2,
            ROWS, DMODEL, DFFN, DMODEL, 0, 0, 0, 1);
    }
    // 9. final layernorm(x + ffo) -> out (xn planes dead)
    ln_kernel<<<ROWS, 256, 0, stream>>>(x, ffo, ln2w, ln2b, (float*)d_out);
}

// Round 8
// 1538.286 us; speedup vs baseline: 1.1131x; 1.1131x over previous
//
#include <hip/hip_runtime.h>
#include <math.h>

#define BATCH   4
#define SEQ     2048
#define DMODEL  768
#define DSTATE  16
#define DCONV   4
#define HEADDIM 64
#define DINNER  1536
#define NHEADS  24
#define CONVDIM 1568
#define DINPROJ 3128
#define DFFN    3072
#define ROWS    (BATCH*SEQ)   // 8192
#define QCH     128           // scan chunk length
#define NCHUNK  (SEQ/QCH)     // 16

typedef __attribute__((ext_vector_type(8))) short bhalf8;   // 8 bf16 (4 VGPRs)
typedef __attribute__((ext_vector_type(4))) float floatx4;  // 4 fp32 acc

__device__ __forceinline__ float gelu_f(float x) {
    return 0.5f * x * (1.0f + erff(x * 0.70710678118654752f));
}

// RNE split: v ~= hi + lo (bf16 each), both rounded-to-nearest-even
__device__ __forceinline__ void splitRNE(float v, unsigned short& h, unsigned short& l) {
    unsigned u = __float_as_uint(v);
    unsigned rr = u + 0x7FFFu + ((u >> 16) & 1u);
    unsigned short hi = (unsigned short)(rr >> 16);
    float rem = v - __uint_as_float(((unsigned)hi) << 16);
    unsigned u2 = __float_as_uint(rem);
    unsigned r2 = u2 + 0x7FFFu + ((u2 >> 16) & 1u);
    h = hi;
    l = (unsigned short)(r2 >> 16);
}

// async global->LDS DMA, 16B per lane (dest = wave-uniform base + lane*16)
__device__ __forceinline__ void gl16(const unsigned short* g, unsigned short* l) {
    __builtin_amdgcn_global_load_lds(
        (const __attribute__((address_space(1))) void*)g,
        (__attribute__((address_space(3))) void*)l, 16, 0, 0);
}

// ---------------- block reduction (256 threads, wave64) ----------------
__device__ __forceinline__ float2 blockReduce2(float a, float b) {
    #pragma unroll
    for (int o = 32; o > 0; o >>= 1) {
        a += __shfl_down(a, o, 64);
        b += __shfl_down(b, o, 64);
    }
    __shared__ float sa[4], sb[4];
    int w = threadIdx.x >> 6, lane = threadIdx.x & 63;
    if (lane == 0) { sa[w] = a; sb[w] = b; }
    __syncthreads();
    if (threadIdx.x == 0) {
        int nw = blockDim.x >> 6;
        for (int i = 1; i < nw; ++i) { a += sa[i]; b += sb[i]; }
        sa[0] = a; sb[0] = b;
    }
    __syncthreads();
    return make_float2(sa[0], sb[0]);
}

// ---------------- LayerNorm, fp32 out (final, with residual) -------------
__global__ __launch_bounds__(256) void ln_kernel(
    const float* __restrict__ x, const float* __restrict__ res,
    const float* __restrict__ w, const float* __restrict__ b,
    float* __restrict__ out)
{
    int r = blockIdx.x;
    const float* xr = x + (size_t)r * DMODEL;
    float v[3]; float s = 0.f, ss = 0.f;
    #pragma unroll
    for (int i = 0; i < 3; ++i) {
        int c = threadIdx.x + i * 256;
        float t = xr[c];
        if (res) t += res[(size_t)r * DMODEL + c];
        v[i] = t; s += t; ss += t * t;
    }
    float2 red = blockReduce2(s, ss);
    float mean = red.x * (1.0f / DMODEL);
    float var  = red.y * (1.0f / DMODEL) - mean * mean;
    float inv  = rsqrtf(var + 1e-5f);
    #pragma unroll
    for (int i = 0; i < 3; ++i) {
        int c = threadIdx.x + i * 256;
        out[(size_t)r * DMODEL + c] = (v[i] - mean) * inv * w[c] + b[c];
    }
}

// ---------------- LayerNorm, bf16 hi/lo plane out (xn for in_proj) -------
__global__ __launch_bounds__(256) void ln_split_kernel(
    const float* __restrict__ x,
    const float* __restrict__ w, const float* __restrict__ b,
    unsigned short* __restrict__ H, unsigned short* __restrict__ L)
{
    int r = blockIdx.x;
    const float* xr = x + (size_t)r * DMODEL;
    float v[3]; float s = 0.f, ss = 0.f;
    #pragma unroll
    for (int i = 0; i < 3; ++i) {
        int c = threadIdx.x + i * 256;
        float t = xr[c];
        v[i] = t; s += t; ss += t * t;
    }
    float2 red = blockReduce2(s, ss);
    float mean = red.x * (1.0f / DMODEL);
    float var  = red.y * (1.0f / DMODEL) - mean * mean;
    float inv  = rsqrtf(var + 1e-5f);
    #pragma unroll
    for (int i = 0; i < 3; ++i) {
        int c = threadIdx.x + i * 256;
        float o = (v[i] - mean) * inv * w[c] + b[c];
        unsigned short h, l;
        splitRNE(o, h, l);
        H[(size_t)r * DMODEL + c] = h;
        L[(size_t)r * DMODEL + c] = l;
    }
}

// ---------------- weight transpose + bf16 hi/lo split ---------------------
__global__ __launch_bounds__(256) void wconv(
    const float* __restrict__ W, unsigned short* __restrict__ TH,
    unsigned short* __restrict__ TL, int K, int N)
{
    __shared__ float t[32][33];
    int tx = threadIdx.x & 31, ty = threadIdx.x >> 5;  // ty 0..7
    int kb = blockIdx.y * 32, nb = blockIdx.x * 32;
    #pragma unroll
    for (int i = 0; i < 4; ++i) {
        int k = kb + ty + i * 8, n = nb + tx;
        t[ty + i * 8][tx] = (k < K && n < N) ? W[(size_t)k * N + n] : 0.f;
    }
    __syncthreads();
    #pragma unroll
    for (int i = 0; i < 4; ++i) {
        int n = nb + ty + i * 8, k = kb + tx;
        if (n < N && k < K) {
            unsigned short hi, lo;
            splitRNE(t[tx][ty + i * 8], hi, lo);
            TH[(size_t)n * K + k] = hi;
            TL[(size_t)n * K + k] = lo;
        }
    }
}

// ---------------- bf16x3 split-GEMM via MFMA (r1 proven structure) --------
// Single 32 KB staging buffer, 2 barriers/k-tile, stage(kt+1) issued after
// the second barrier so DMA latency hides under the MFMA cluster. 5 blocks/
// CU (LDS-capped) provides the cross-block overlap that covers the drains.
__global__ __launch_bounds__(256) void gemm3(
    const unsigned short* __restrict__ AHg, const unsigned short* __restrict__ ALg,
    const unsigned short* __restrict__ BHg, const unsigned short* __restrict__ BLg,
    float* __restrict__ C, unsigned short* __restrict__ CHo, unsigned short* __restrict__ CLo,
    const float* __restrict__ bias,
    int M, int N, int K, int ldc, int coloff,
    int revA, int revC, int act)
{
    (void)M;
    __shared__ __align__(16) unsigned short AsH[128 * 32], AsL[128 * 32];
    __shared__ __align__(16) unsigned short BsH[128 * 32], BsL[128 * 32];

    const int tid = threadIdx.x;
    const int m0 = blockIdx.y * 128;
    const int n0 = blockIdx.x * 128;

    size_t aoff[2], boff[2];
    int lofs[2];
    #pragma unroll
    for (int q = 0; q < 2; ++q) {
        int row = (tid >> 2) + 64 * q;
        int sd  = (tid & 3) ^ ((row >> 1) & 3);   // inverse-swizzled data slot
        int ar = m0 + row;
        if (revA) ar = (ar & ~(SEQ - 1)) + (SEQ - 1 - (ar & (SEQ - 1)));
        aoff[q] = (size_t)ar * K + sd * 8;
        boff[q] = (size_t)(n0 + row) * K + sd * 8;
        lofs[q] = (tid + 256 * q) * 8;
    }

    auto stage = [&](int k0) {
        #pragma unroll
        for (int q = 0; q < 2; ++q) {
            gl16(AHg + aoff[q] + k0, AsH + lofs[q]);
            gl16(ALg + aoff[q] + k0, AsL + lofs[q]);
            gl16(BHg + boff[q] + k0, BsH + lofs[q]);
            gl16(BLg + boff[q] + k0, BsL + lofs[q]);
        }
    };

    auto frag = [&](const unsigned short* buf, int row, int slot) -> bhalf8 {
        int sp = slot ^ ((row >> 1) & 3);
        return *(const bhalf8*)(buf + row * 32 + sp * 8);
    };

    const int w = tid >> 6, lane = tid & 63;
    const int rw = (w >> 1) * 64, cw = (w & 1) * 64;
    const int lr = lane & 15;
    const int lq = lane >> 4;

    floatx4 acc[4][4];
    const floatx4 fz = {0.f, 0.f, 0.f, 0.f};
    #pragma unroll
    for (int i = 0; i < 4; ++i)
        #pragma unroll
        for (int j = 0; j < 4; ++j) acc[i][j] = fz;

    const int ktiles = K >> 5;
    stage(0);
    for (int kt = 0; kt < ktiles; ++kt) {
        __syncthreads();                     // drains vmcnt(0): tile visible
        bhalf8 ah[4], al[4], bh[4], bl[4];
        #pragma unroll
        for (int i = 0; i < 4; ++i) {
            int ra = rw + i * 16 + lr;
            int rb = cw + i * 16 + lr;
            ah[i] = frag(AsH, ra, lq);
            al[i] = frag(AsL, ra, lq);
            bh[i] = frag(BsH, rb, lq);
            bl[i] = frag(BsL, rb, lq);
        }
        __syncthreads();                     // all lanes' ds_reads retired
        if (kt + 1 < ktiles) stage((kt + 1) * 32);  // DMA overlaps MFMAs below
        #pragma unroll
        for (int i = 0; i < 4; ++i)
            #pragma unroll
            for (int j = 0; j < 4; ++j) {
                acc[i][j] = __builtin_amdgcn_mfma_f32_16x16x32_bf16(ah[i], bh[j], acc[i][j], 0, 0, 0);
                acc[i][j] = __builtin_amdgcn_mfma_f32_16x16x32_bf16(ah[i], bl[j], acc[i][j], 0, 0, 0);
                acc[i][j] = __builtin_amdgcn_mfma_f32_16x16x32_bf16(al[i], bh[j], acc[i][j], 0, 0, 0);
            }
    }

    #pragma unroll
    for (int i = 0; i < 4; ++i) {
        #pragma unroll
        for (int j = 0; j < 4; ++j) {
            int gc = n0 + cw + j * 16 + lr;
            if (gc < N) {
                float bv = bias ? bias[gc] : 0.f;
                #pragma unroll
                for (int rg = 0; rg < 4; ++rg) {
                    int gm = m0 + rw + i * 16 + lq * 4 + rg;
                    if (revC) gm = (gm & ~(SEQ - 1)) + (SEQ - 1 - (gm & (SEQ - 1)));
                    float v = acc[i][j][rg] + bv;
                    if (act) v = gelu_f(v);
                    size_t o = (size_t)gm * ldc + coloff + gc;
                    if (CHo) {
                        unsigned short h, l;
                        splitRNE(v, h, l);
                        CHo[o] = h; CLo[o] = l;
                    } else {
                        C[o] = v;
                    }
                }
            }
        }
    }
}

// ---------------- merged bidirectional out_proj GEMM ----------------------
// Both directions' out_proj in ONE dispatch (768 blocks = single machine
// round vs 2 x 384-block starved dispatches). blockIdx.y >= 64 -> dir 1:
// own A planes (zn1), own weights, coloff 768, flipped C rows.
__global__ __launch_bounds__(256) void gemm3d(
    const unsigned short* __restrict__ A0H, const unsigned short* __restrict__ A0L,
    const unsigned short* __restrict__ A1H, const unsigned short* __restrict__ A1L,
    const unsigned short* __restrict__ W0H, const unsigned short* __restrict__ W0L,
    const unsigned short* __restrict__ W1H, const unsigned short* __restrict__ W1L,
    unsigned short* __restrict__ CHo, unsigned short* __restrict__ CLo)
{
    const int N = DMODEL, K = DINNER, ldc = DINNER;
    const int dir = blockIdx.y >> 6;
    const unsigned short* AHg = dir ? A1H : A0H;
    const unsigned short* ALg = dir ? A1L : A0L;
    const unsigned short* BHg = dir ? W1H : W0H;
    const unsigned short* BLg = dir ? W1L : W0L;
    const int coloff = dir * DMODEL;

    __shared__ __align__(16) unsigned short AsH[128 * 32], AsL[128 * 32];
    __shared__ __align__(16) unsigned short BsH[128 * 32], BsL[128 * 32];

    const int tid = threadIdx.x;
    const int m0 = (blockIdx.y & 63) * 128;
    const int n0 = blockIdx.x * 128;

    size_t aoff[2], boff[2];
    int lofs[2];
    #pragma unroll
    for (int q = 0; q < 2; ++q) {
        int row = (tid >> 2) + 64 * q;
        int sd  = (tid & 3) ^ ((row >> 1) & 3);
        aoff[q] = (size_t)(m0 + row) * K + sd * 8;
        boff[q] = (size_t)(n0 + row) * K + sd * 8;
        lofs[q] = (tid + 256 * q) * 8;
    }

    auto stage = [&](int k0) {
        #pragma unroll
        for (int q = 0; q < 2; ++q) {
            gl16(AHg + aoff[q] + k0, AsH + lofs[q]);
            gl16(ALg + aoff[q] + k0, AsL + lofs[q]);
            gl16(BHg + boff[q] + k0, BsH + lofs[q]);
            gl16(BLg + boff[q] + k0, BsL + lofs[q]);
        }
    };

    auto frag = [&](const unsigned short* buf, int row, int slot) -> bhalf8 {
        int sp = slot ^ ((row >> 1) & 3);
        return *(const bhalf8*)(buf + row * 32 + sp * 8);
    };

    const int w = tid >> 6, lane = tid & 63;
    const int rw = (w >> 1) * 64, cw = (w & 1) * 64;
    const int lr = lane & 15;
    const int lq = lane >> 4;

    floatx4 acc[4][4];
    const floatx4 fz = {0.f, 0.f, 0.f, 0.f};
    #pragma unroll
    for (int i = 0; i < 4; ++i)
        #pragma unroll
        for (int j = 0; j < 4; ++j) acc[i][j] = fz;

    const int ktiles = K >> 5;   // 48
    stage(0);
    for (int kt = 0; kt < ktiles; ++kt) {
        __syncthreads();
        bhalf8 ah[4], al[4], bh[4], bl[4];
        #pragma unroll
        for (int i = 0; i < 4; ++i) {
            int ra = rw + i * 16 + lr;
            int rb = cw + i * 16 + lr;
            ah[i] = frag(AsH, ra, lq);
            al[i] = frag(AsL, ra, lq);
            bh[i] = frag(BsH, rb, lq);
            bl[i] = frag(BsL, rb, lq);
        }
        __syncthreads();
        if (kt + 1 < ktiles) stage((kt + 1) * 32);
        #pragma unroll
        for (int i = 0; i < 4; ++i)
            #pragma unroll
            for (int j = 0; j < 4; ++j) {
                acc[i][j] = __builtin_amdgcn_mfma_f32_16x16x32_bf16(ah[i], bh[j], acc[i][j], 0, 0, 0);
                acc[i][j] = __builtin_amdgcn_mfma_f32_16x16x32_bf16(ah[i], bl[j], acc[i][j], 0, 0, 0);
                acc[i][j] = __builtin_amdgcn_mfma_f32_16x16x32_bf16(al[i], bh[j], acc[i][j], 0, 0, 0);
            }
    }

    #pragma unroll
    for (int i = 0; i < 4; ++i) {
        #pragma unroll
        for (int j = 0; j < 4; ++j) {
            int gc = n0 + cw + j * 16 + lr;
            #pragma unroll
            for (int rg = 0; rg < 4; ++rg) {
                int gm = m0 + rw + i * 16 + lq * 4 + rg;
                if (dir) gm = (gm & ~(SEQ - 1)) + (SEQ - 1 - (gm & (SEQ - 1)));
                float v = acc[i][j][rg];
                size_t o = (size_t)gm * ldc + coloff + gc;
                unsigned short h, l;
                splitRNE(v, h, l);
                CHo[o] = h; CLo[o] = l;
            }
        }
    }
}

// ---------------- depthwise causal conv + SiLU (float4) + fused dt/dA -----
__global__ __launch_bounds__(256) void conv_kernel(
    const float* __restrict__ zx, const float* __restrict__ cw,
    const float* __restrict__ cb, float* __restrict__ xcv,
    float* __restrict__ bc,
    const float* __restrict__ dt_bias, const float* __restrict__ A_log,
    float* __restrict__ dtda)
{
    int cg = blockIdx.x * 256 + threadIdx.x;   // channel group of 4
    int r = blockIdx.y;
    if (cg < CONVDIM / 4) {
        int c = cg * 4;
        int t = r & (SEQ - 1);
        int rb = r & ~(SEQ - 1);
        float4 acc = *(const float4*)&cb[c];
        #pragma unroll
        for (int k = 0; k < DCONV; ++k) {
            int tt = t - (DCONV - 1) + k;
            if (tt >= 0) {
                float4 xv = *(const float4*)&zx[(size_t)(rb + tt) * DINPROJ + DINNER + c];
                acc.x += cw[(c + 0) * DCONV + k] * xv.x;
                acc.y += cw[(c + 1) * DCONV + k] * xv.y;
                acc.z += cw[(c + 2) * DCONV + k] * xv.z;
                acc.w += cw[(c + 3) * DCONV + k] * xv.w;
            }
        }
        float4 v;
        v.x = acc.x / (1.0f + expf(-acc.x));
        v.y = acc.y / (1.0f + expf(-acc.y));
        v.z = acc.z / (1.0f + expf(-acc.z));
        v.w = acc.w / (1.0f + expf(-acc.w));
        if (c < DINNER) *(float4*)&xcv[(size_t)r * DINNER + c] = v;
        else            *(float4*)&bc[(size_t)r * 32 + (c - DINNER)] = v;
    } else if (cg >= CONVDIM / 4 && cg < CONVDIM / 4 + NHEADS / 4) {
        int h0 = (cg - CONVDIM / 4) * 4;
        float4 zv = *(const float4*)&zx[(size_t)r * DINPROJ + (DINPROJ - NHEADS) + h0];
        float zz[4] = {zv.x, zv.y, zv.z, zv.w};
        #pragma unroll
        for (int j = 0; j < 4; ++j) {
            int h = h0 + j;
            float v = zz[j] + dt_bias[h];
            float dt = (v > 20.f) ? v : log1pf(expf(v));
            float A = -expf(A_log[h]);
            float2 o = make_float2(dt, expf(dt * A));
            *(float2*)&dtda[(size_t)r * 48 + 2 * h] = o;
        }
    }
}

// ---------------- chunked scan, phase A: per-chunk local scan -------------
__global__ __launch_bounds__(64) void scan_a(
    const float* __restrict__ xcv, const float* __restrict__ bc,
    const float* __restrict__ dtda, const float* __restrict__ Dp,
    float* __restrict__ yout, float* __restrict__ S, float* __restrict__ cd)
{
    int blk = blockIdx.x;
    int bh = blk / NCHUNK, c = blk - bh * NCHUNK;
    int b = bh / NHEADS, h = bh - b * NHEADS;
    int p = threadIdx.x;
    float hs[DSTATE] = {};
    float Dv = Dp[h];
    float cum = 1.f;
    int t0 = c * QCH;
    for (int t = t0; t < t0 + QCH; ++t) {
        size_t r = (size_t)b * SEQ + t;
        float2 dd = *(const float2*)&dtda[r * 48 + 2 * h];
        float dt = dd.x;
        float dA = dd.y;
        float x  = xcv[r * DINNER + h * HEADDIM + p];
        cum *= dA;
        float coef = dt * x;
        const float* bcr = bc + r * 32;
        float y = 0.f;
        #pragma unroll
        for (int n = 0; n < DSTATE; ++n) {
            hs[n] = hs[n] * dA + coef * bcr[n];
            y += hs[n] * bcr[16 + n];
        }
        yout[r * DINPROJ + DINNER + h * HEADDIM + p] = y + Dv * x;
        if (p == 0) cd[r * NHEADS + h] = cum;
    }
    float* Sp = S + (((size_t)bh * NCHUNK + c) * HEADDIM + p) * DSTATE;
    #pragma unroll
    for (int n = 0; n < DSTATE; ++n) Sp[n] = hs[n];
}

// ---------------- chunked scan, phase B: sequential chunk combine ---------
__global__ __launch_bounds__(64) void scan_b(
    const float* __restrict__ cd, float* __restrict__ S)
{
    int bh = blockIdx.x;
    int b = bh / NHEADS, h = bh - b * NHEADS;
    int p = threadIdx.x;
    float H[DSTATE] = {};
    for (int c = 0; c < NCHUNK; ++c) {
        float* Sp = S + (((size_t)bh * NCHUNK + c) * HEADDIM + p) * DSTATE;
        float P = cd[((size_t)b * SEQ + c * QCH + QCH - 1) * NHEADS + h];
        float s[DSTATE];
        #pragma unroll
        for (int n = 0; n < DSTATE; ++n) s[n] = Sp[n];
        #pragma unroll
        for (int n = 0; n < DSTATE; ++n) Sp[n] = H[n];
        #pragma unroll
        for (int n = 0; n < DSTATE; ++n) H[n] = P * H[n] + s[n];
    }
}

// ---------------- chunked scan, phase C: carry correction -----------------
__global__ __launch_bounds__(64) void scan_c(
    const float* __restrict__ bc, const float* __restrict__ cd,
    const float* __restrict__ S, float* __restrict__ yout)
{
    int blk = blockIdx.x;
    int bh = blk / (NCHUNK - 1), c = blk - bh * (NCHUNK - 1) + 1;
    int b = bh / NHEADS, h = bh - b * NHEADS;
    int p = threadIdx.x;
    const float* Hp = S + (((size_t)bh * NCHUNK + c) * HEADDIM + p) * DSTATE;
    float H[DSTATE];
    #pragma unroll
    for (int n = 0; n < DSTATE; ++n) H[n] = Hp[n];
    int t0 = c * QCH;
    for (int t = t0; t < t0 + QCH; ++t) {
        size_t r = (size_t)b * SEQ + t;
        const float* Cr = bc + r * 32 + 16;
        float dot = 0.f;
        #pragma unroll
        for (int n = 0; n < DSTATE; ++n) dot += H[n] * Cr[n];
        float cum = cd[r * NHEADS + h];
        yout[r * DINPROJ + DINNER + h * HEADDIM + p] += cum * dot;
    }
}

// ---------------- gated RMSNorm -> bf16 hi/lo planes ----------------------
__global__ __launch_bounds__(256) void gnorm_kernel(
    const float* __restrict__ zx, const float* __restrict__ nw,
    unsigned short* __restrict__ H, unsigned short* __restrict__ L)
{
    int r = blockIdx.x;
    const float* zr = zx + (size_t)r * DINPROJ;
    float v[6]; float ss = 0.f;
    #pragma unroll
    for (int i = 0; i < 6; ++i) {
        int c = threadIdx.x + i * 256;
        float z = zr[c];
        float y = zr[DINNER + c];
        float t = y * z / (1.0f + expf(-z));
        v[i] = t; ss += t * t;
    }
    float2 red = blockReduce2(ss, 0.f);
    float sc = rsqrtf(red.x * (1.0f / DINNER) + 1e-5f);
    #pragma unroll
    for (int i = 0; i < 6; ++i) {
        int c = threadIdx.x + i * 256;
        float o = v[i] * sc * nw[c];
        unsigned short h, l;
        splitRNE(o, h, l);
        H[(size_t)r * DINNER + c] = h;
        L[(size_t)r * DINNER + c] = l;
    }
}

extern "C" void kernel_launch(void* const* d_in, const int* in_sizes, int n_in,
                              void* d_out, int out_size, void* d_ws, size_t ws_size,
                              hipStream_t stream)
{
    (void)in_sizes; (void)n_in; (void)out_size; (void)ws_size;
    const float* x     = (const float*)d_in[0];
    const float* ln1w  = (const float*)d_in[1];
    const float* ln1b  = (const float*)d_in[2];
    const float* ln2w  = (const float*)d_in[3];
    const float* ln2b  = (const float*)d_in[4];
    const float* ffnw1 = (const float*)d_in[5];
    const float* ffnb1 = (const float*)d_in[6];
    const float* ffnw2 = (const float*)d_in[7];
    const float* ffnb2 = (const float*)d_in[8];
    const float* p[2][8];
    for (int d = 0; d < 2; ++d)
        for (int i = 0; i < 8; ++i)
            p[d][i] = (const float*)d_in[9 + d * 8 + i];

    // Region map (floats from ws):
    //   zx   : [0, 25.62M)        102.5 MB — in_proj/scan target per dir;
    //          AFTER the dir loop: bi planes in [0,12.58M), hmH in
    //          [12.58M,25.17M)
    //   bi   : [25.62M, 38.21M)   50.3 MB — zn0 planes during d1; hmL after
    //   S    : [38.21M, 50.79M)   50.3 MB — xcv per dir -> zn1 planes ->
    //          ffn weight planes + ffo
    //   Wbuf : [50.79M, +2.40M)   9.6 MB — in_proj planes per dir; then
    //          BOTH dirs' out_proj planes (4 x 1.18M ushort = 9.4 MB);
    //          Sbuf/cdbf alias during scans
    float* ws   = (float*)d_ws;
    float* zx   = ws;
    float* bi   = zx + (size_t)ROWS * DINPROJ;
    float* S    = bi + (size_t)ROWS * DINNER;
    float* Wbuf = S  + (size_t)ROWS * DINNER;
    float* bcb  = Wbuf + 2402304;
    float* dtda = bcb + (size_t)ROWS * 32;
    float* Sbuf = Wbuf;                       // alias (dead in_proj weights)
    float* cdbf = Wbuf + (size_t)BATCH * NHEADS * NCHUNK * HEADDIM * DSTATE;

    unsigned short* xnH = (unsigned short*)d_out;              // xn planes in d_out
    unsigned short* xnL = xnH + (size_t)ROWS * DMODEL;
    float* xcv = S;
    // zn planes: dir 0 -> bi region, dir 1 -> S (xcv dead by gnorm time)
    unsigned short* znH[2] = {(unsigned short*)bi, (unsigned short*)S};
    unsigned short* znL[2] = {znH[0] + (size_t)ROWS * DINNER,
                              znH[1] + (size_t)ROWS * DINNER};
    // bi planes -> zx lower half (zx dead after d1 gnorm)
    unsigned short* biH = (unsigned short*)zx;
    unsigned short* biL = biH + (size_t)ROWS * DINNER;
    // hmid planes: hi -> zx upper half, lo -> bi region (zn0 dead)
    unsigned short* hmH = (unsigned short*)(zx + (size_t)ROWS * DINNER);
    unsigned short* hmL = (unsigned short*)bi;
    float* ffo = S + 4718592;   // after ffn weight-plane region (18.9 MB)

    // 1. ln1: x -> xn bf16 hi/lo planes (in d_out)
    ln_split_kernel<<<ROWS, 256, 0, stream>>>(x, ln1w, ln1b, xnH, xnL);

    for (int d = 0; d < 2; ++d) {
        unsigned short* WH = (unsigned short*)Wbuf;
        unsigned short* WL = WH + (size_t)DINPROJ * DMODEL;
        wconv<<<dim3((DINPROJ + 31) / 32, DMODEL / 32), 256, 0, stream>>>(
            p[d][0], WH, WL, DMODEL, DINPROJ);
        // 2. in_proj: zx = xn(flip if d==1) @ in_w   [8192 x 3128] fp32 out
        gemm3<<<dim3((DINPROJ + 127) / 128, ROWS / 128), 256, 0, stream>>>(
            xnH, xnL, WH, WL, zx, nullptr, nullptr, nullptr,
            ROWS, DINPROJ, DMODEL, DINPROJ, 0, d, 0, 0);
        // 3. conv + silu -> xcv (S), bcb; fused dt/dA -> dtda
        conv_kernel<<<dim3(2, ROWS), 256, 0, stream>>>(
            zx, p[d][1], p[d][2], xcv, bcb, p[d][3], p[d][4], dtda);
        // 4. chunked scan -> y (+D*x) into zx cols [1536,3072)
        scan_a<<<BATCH * NHEADS * NCHUNK, 64, 0, stream>>>(
            xcv, bcb, dtda, p[d][5], zx, Sbuf, cdbf);
        scan_b<<<BATCH * NHEADS, 64, 0, stream>>>(cdbf, Sbuf);
        scan_c<<<BATCH * NHEADS * (NCHUNK - 1), 64, 0, stream>>>(
            bcb, cdbf, Sbuf, zx);
        // 5. gated RMSNorm -> zn planes (d0 -> bi region, d1 -> S)
        gnorm_kernel<<<ROWS, 256, 0, stream>>>(zx, p[d][6], znH[d], znL[d]);
    }

    // 6. merged out_proj (both directions, one dispatch):
    //    bi planes (zx lower) = zn[d] @ out_w[d], flip-store for d1.
    //    Weights for BOTH dirs staged into Wbuf (scan aliases dead).
    {
        unsigned short* W0H = (unsigned short*)Wbuf;
        unsigned short* W0L = W0H + (size_t)DMODEL * DINNER;
        unsigned short* W1H = W0L + (size_t)DMODEL * DINNER;
        unsigned short* W1L = W1H + (size_t)DMODEL * DINNER;
        wconv<<<dim3(DMODEL / 32, DINNER / 32), 256, 0, stream>>>(
            p[0][7], W0H, W0L, DINNER, DMODEL);
        wconv<<<dim3(DMODEL / 32, DINNER / 32), 256, 0, stream>>>(
            p[1][7], W1H, W1L, DINNER, DMODEL);
        gemm3d<<<dim3(DMODEL / 128, 2 * ROWS / 128), 256, 0, stream>>>(
            znH[0], znL[0], znH[1], znL[1],
            W0H, W0L, W1H, W1L, biH, biL);
    }

    // 7. ffn1: hmid planes = split(gelu(bi @ w1 + b1))  [8192 x 3072]
    //    reads zx lower, writes zx upper (hi) + bi region (lo) — disjoint.
    {
        unsigned short* WH = (unsigned short*)S;
        unsigned short* WL = WH + (size_t)DFFN * DINNER;
        wconv<<<dim3(DFFN / 32, DINNER / 32), 256, 0, stream>>>(
            ffnw1, WH, WL, DINNER, DFFN);
        gemm3<<<dim3(DFFN / 128, ROWS / 128), 256, 0, stream>>>(
            biH, biL, WH, WL, nullptr, hmH, hmL, ffnb1,
            ROWS, DFFN, DINNER, DFFN, 0, 0, 0, 1);
    }
    // 8. ffn2: ffo = gelu(hmid @ w2 + b2) [8192 x 768] fp32 (weights in S)
    {
        unsigned short* WH = (unsigned short*)S;
        unsigned short* WL = WH + (size_t)DMODEL * DFFN;
        wconv<<<dim3(DMODEL / 32, DFFN / 32), 256, 0, stream>>>(
            ffnw2, WH, WL, DFFN, DMODEL);
        gemm3<<<dim3(DMODEL / 128, ROWS / 128), 256, 0, stream>>>(
            hmH, hmL, WH, WL, ffo, nullptr, nullptr, ffnb2,
            ROWS, DMODEL, DFFN, DMODEL, 0, 0, 0, 1);
    }
    // 9. final layernorm(x + ffo) -> out (xn planes dead)
    ln_kernel<<<ROWS, 256, 0, stream>>>(x, ffo, ln2w, ln2b, (float*)d_out);
}

// Round 9
// 1383.756 us; speedup vs baseline: 1.2374x; 1.1117x over previous
//
#include <hip/hip_runtime.h>
#include <math.h>

#define BATCH   4
#define SEQ     2048
#define DMODEL  768
#define DSTATE  16
#define DCONV   4
#define HEADDIM 64
#define DINNER  1536
#define NHEADS  24
#define CONVDIM 1568
#define DINPROJ 3128
#define DFFN    3072
#define ROWS    (BATCH*SEQ)   // 8192
#define QCH     128           // scan chunk length
#define NCHUNK  (SEQ/QCH)     // 16

typedef __attribute__((ext_vector_type(8))) short bhalf8;   // 8 bf16 (4 VGPRs)
typedef __attribute__((ext_vector_type(4))) float floatx4;  // 4 fp32 acc

__device__ __forceinline__ float gelu_f(float x) {
    return 0.5f * x * (1.0f + erff(x * 0.70710678118654752f));
}

// RNE split: v ~= hi + lo (bf16 each), both rounded-to-nearest-even
__device__ __forceinline__ void splitRNE(float v, unsigned short& h, unsigned short& l) {
    unsigned u = __float_as_uint(v);
    unsigned rr = u + 0x7FFFu + ((u >> 16) & 1u);
    unsigned short hi = (unsigned short)(rr >> 16);
    float rem = v - __uint_as_float(((unsigned)hi) << 16);
    unsigned u2 = __float_as_uint(rem);
    unsigned r2 = u2 + 0x7FFFu + ((u2 >> 16) & 1u);
    h = hi;
    l = (unsigned short)(r2 >> 16);
}

// async global->LDS DMA, 16B per lane (dest = wave-uniform base + lane*16)
__device__ __forceinline__ void gl16(const unsigned short* g, unsigned short* l) {
    __builtin_amdgcn_global_load_lds(
        (const __attribute__((address_space(1))) void*)g,
        (__attribute__((address_space(3))) void*)l, 16, 0, 0);
}

// ---------------- block reduction (256 threads, wave64) ----------------
__device__ __forceinline__ float2 blockReduce2(float a, float b) {
    #pragma unroll
    for (int o = 32; o > 0; o >>= 1) {
        a += __shfl_down(a, o, 64);
        b += __shfl_down(b, o, 64);
    }
    __shared__ float sa[4], sb[4];
    int w = threadIdx.x >> 6, lane = threadIdx.x & 63;
    if (lane == 0) { sa[w] = a; sb[w] = b; }
    __syncthreads();
    if (threadIdx.x == 0) {
        int nw = blockDim.x >> 6;
        for (int i = 1; i < nw; ++i) { a += sa[i]; b += sb[i]; }
        sa[0] = a; sb[0] = b;
    }
    __syncthreads();
    return make_float2(sa[0], sb[0]);
}

// ---------------- LayerNorm, fp32 out (final, with residual) -------------
__global__ __launch_bounds__(256) void ln_kernel(
    const float* __restrict__ x, const float* __restrict__ res,
    const float* __restrict__ w, const float* __restrict__ b,
    float* __restrict__ out)
{
    int r = blockIdx.x;
    const float* xr = x + (size_t)r * DMODEL;
    float v[3]; float s = 0.f, ss = 0.f;
    #pragma unroll
    for (int i = 0; i < 3; ++i) {
        int c = threadIdx.x + i * 256;
        float t = xr[c];
        if (res) t += res[(size_t)r * DMODEL + c];
        v[i] = t; s += t; ss += t * t;
    }
    float2 red = blockReduce2(s, ss);
    float mean = red.x * (1.0f / DMODEL);
    float var  = red.y * (1.0f / DMODEL) - mean * mean;
    float inv  = rsqrtf(var + 1e-5f);
    #pragma unroll
    for (int i = 0; i < 3; ++i) {
        int c = threadIdx.x + i * 256;
        out[(size_t)r * DMODEL + c] = (v[i] - mean) * inv * w[c] + b[c];
    }
}

// ---------------- LayerNorm, bf16 hi/lo plane out (xn for in_proj) -------
__global__ __launch_bounds__(256) void ln_split_kernel(
    const float* __restrict__ x,
    const float* __restrict__ w, const float* __restrict__ b,
    unsigned short* __restrict__ H, unsigned short* __restrict__ L)
{
    int r = blockIdx.x;
    const float* xr = x + (size_t)r * DMODEL;
    float v[3]; float s = 0.f, ss = 0.f;
    #pragma unroll
    for (int i = 0; i < 3; ++i) {
        int c = threadIdx.x + i * 256;
        float t = xr[c];
        v[i] = t; s += t; ss += t * t;
    }
    float2 red = blockReduce2(s, ss);
    float mean = red.x * (1.0f / DMODEL);
    float var  = red.y * (1.0f / DMODEL) - mean * mean;
    float inv  = rsqrtf(var + 1e-5f);
    #pragma unroll
    for (int i = 0; i < 3; ++i) {
        int c = threadIdx.x + i * 256;
        float o = (v[i] - mean) * inv * w[c] + b[c];
        unsigned short h, l;
        splitRNE(o, h, l);
        H[(size_t)r * DMODEL + c] = h;
        L[(size_t)r * DMODEL + c] = l;
    }
}

// ---------------- weight transpose + bf16 hi/lo split ---------------------
__global__ __launch_bounds__(256) void wconv(
    const float* __restrict__ W, unsigned short* __restrict__ TH,
    unsigned short* __restrict__ TL, int K, int N)
{
    __shared__ float t[32][33];
    int tx = threadIdx.x & 31, ty = threadIdx.x >> 5;  // ty 0..7
    int kb = blockIdx.y * 32, nb = blockIdx.x * 32;
    #pragma unroll
    for (int i = 0; i < 4; ++i) {
        int k = kb + ty + i * 8, n = nb + tx;
        t[ty + i * 8][tx] = (k < K && n < N) ? W[(size_t)k * N + n] : 0.f;
    }
    __syncthreads();
    #pragma unroll
    for (int i = 0; i < 4; ++i) {
        int n = nb + ty + i * 8, k = kb + tx;
        if (n < N && k < K) {
            unsigned short hi, lo;
            splitRNE(t[tx][ty + i * 8], hi, lo);
            TH[(size_t)n * K + k] = hi;
            TL[(size_t)n * K + k] = lo;
        }
    }
}

// ---------------- bf16x3 split-GEMM via MFMA (r1 proven structure) --------
__global__ __launch_bounds__(256) void gemm3(
    const unsigned short* __restrict__ AHg, const unsigned short* __restrict__ ALg,
    const unsigned short* __restrict__ BHg, const unsigned short* __restrict__ BLg,
    float* __restrict__ C, unsigned short* __restrict__ CHo, unsigned short* __restrict__ CLo,
    const float* __restrict__ bias,
    int M, int N, int K, int ldc, int coloff,
    int revA, int revC, int act)
{
    (void)M;
    __shared__ __align__(16) unsigned short AsH[128 * 32], AsL[128 * 32];
    __shared__ __align__(16) unsigned short BsH[128 * 32], BsL[128 * 32];

    const int tid = threadIdx.x;
    const int m0 = blockIdx.y * 128;
    const int n0 = blockIdx.x * 128;

    size_t aoff[2], boff[2];
    int lofs[2];
    #pragma unroll
    for (int q = 0; q < 2; ++q) {
        int row = (tid >> 2) + 64 * q;
        int sd  = (tid & 3) ^ ((row >> 1) & 3);   // inverse-swizzled data slot
        int ar = m0 + row;
        if (revA) ar = (ar & ~(SEQ - 1)) + (SEQ - 1 - (ar & (SEQ - 1)));
        aoff[q] = (size_t)ar * K + sd * 8;
        boff[q] = (size_t)(n0 + row) * K + sd * 8;
        lofs[q] = (tid + 256 * q) * 8;
    }

    auto stage = [&](int k0) {
        #pragma unroll
        for (int q = 0; q < 2; ++q) {
            gl16(AHg + aoff[q] + k0, AsH + lofs[q]);
            gl16(ALg + aoff[q] + k0, AsL + lofs[q]);
            gl16(BHg + boff[q] + k0, BsH + lofs[q]);
            gl16(BLg + boff[q] + k0, BsL + lofs[q]);
        }
    };

    auto frag = [&](const unsigned short* buf, int row, int slot) -> bhalf8 {
        int sp = slot ^ ((row >> 1) & 3);
        return *(const bhalf8*)(buf + row * 32 + sp * 8);
    };

    const int w = tid >> 6, lane = tid & 63;
    const int rw = (w >> 1) * 64, cw = (w & 1) * 64;
    const int lr = lane & 15;
    const int lq = lane >> 4;

    floatx4 acc[4][4];
    const floatx4 fz = {0.f, 0.f, 0.f, 0.f};
    #pragma unroll
    for (int i = 0; i < 4; ++i)
        #pragma unroll
        for (int j = 0; j < 4; ++j) acc[i][j] = fz;

    const int ktiles = K >> 5;
    stage(0);
    for (int kt = 0; kt < ktiles; ++kt) {
        __syncthreads();                     // drains vmcnt(0): tile visible
        bhalf8 ah[4], al[4], bh[4], bl[4];
        #pragma unroll
        for (int i = 0; i < 4; ++i) {
            int ra = rw + i * 16 + lr;
            int rb = cw + i * 16 + lr;
            ah[i] = frag(AsH, ra, lq);
            al[i] = frag(AsL, ra, lq);
            bh[i] = frag(BsH, rb, lq);
            bl[i] = frag(BsL, rb, lq);
        }
        __syncthreads();                     // all lanes' ds_reads retired
        if (kt + 1 < ktiles) stage((kt + 1) * 32);  // DMA overlaps MFMAs below
        #pragma unroll
        for (int i = 0; i < 4; ++i)
            #pragma unroll
            for (int j = 0; j < 4; ++j) {
                acc[i][j] = __builtin_amdgcn_mfma_f32_16x16x32_bf16(ah[i], bh[j], acc[i][j], 0, 0, 0);
                acc[i][j] = __builtin_amdgcn_mfma_f32_16x16x32_bf16(ah[i], bl[j], acc[i][j], 0, 0, 0);
                acc[i][j] = __builtin_amdgcn_mfma_f32_16x16x32_bf16(al[i], bh[j], acc[i][j], 0, 0, 0);
            }
    }

    #pragma unroll
    for (int i = 0; i < 4; ++i) {
        #pragma unroll
        for (int j = 0; j < 4; ++j) {
            int gc = n0 + cw + j * 16 + lr;
            if (gc < N) {
                float bv = bias ? bias[gc] : 0.f;
                #pragma unroll
                for (int rg = 0; rg < 4; ++rg) {
                    int gm = m0 + rw + i * 16 + lq * 4 + rg;
                    if (revC) gm = (gm & ~(SEQ - 1)) + (SEQ - 1 - (gm & (SEQ - 1)));
                    float v = acc[i][j][rg] + bv;
                    if (act) v = gelu_f(v);
                    size_t o = (size_t)gm * ldc + coloff + gc;
                    if (CHo) {
                        unsigned short h, l;
                        splitRNE(v, h, l);
                        CHo[o] = h; CLo[o] = l;
                    } else {
                        C[o] = v;
                    }
                }
            }
        }
    }
}

// ---------------- merged bidirectional out_proj GEMM ----------------------
__global__ __launch_bounds__(256) void gemm3d(
    const unsigned short* __restrict__ A0H, const unsigned short* __restrict__ A0L,
    const unsigned short* __restrict__ A1H, const unsigned short* __restrict__ A1L,
    const unsigned short* __restrict__ W0H, const unsigned short* __restrict__ W0L,
    const unsigned short* __restrict__ W1H, const unsigned short* __restrict__ W1L,
    unsigned short* __restrict__ CHo, unsigned short* __restrict__ CLo)
{
    const int N = DMODEL, K = DINNER, ldc = DINNER;
    const int dir = blockIdx.y >> 6;
    const unsigned short* AHg = dir ? A1H : A0H;
    const unsigned short* ALg = dir ? A1L : A0L;
    const unsigned short* BHg = dir ? W1H : W0H;
    const unsigned short* BLg = dir ? W1L : W0L;
    const int coloff = dir * DMODEL;

    __shared__ __align__(16) unsigned short AsH[128 * 32], AsL[128 * 32];
    __shared__ __align__(16) unsigned short BsH[128 * 32], BsL[128 * 32];

    const int tid = threadIdx.x;
    const int m0 = (blockIdx.y & 63) * 128;
    const int n0 = blockIdx.x * 128;

    size_t aoff[2], boff[2];
    int lofs[2];
    #pragma unroll
    for (int q = 0; q < 2; ++q) {
        int row = (tid >> 2) + 64 * q;
        int sd  = (tid & 3) ^ ((row >> 1) & 3);
        aoff[q] = (size_t)(m0 + row) * K + sd * 8;
        boff[q] = (size_t)(n0 + row) * K + sd * 8;
        lofs[q] = (tid + 256 * q) * 8;
    }

    auto stage = [&](int k0) {
        #pragma unroll
        for (int q = 0; q < 2; ++q) {
            gl16(AHg + aoff[q] + k0, AsH + lofs[q]);
            gl16(ALg + aoff[q] + k0, AsL + lofs[q]);
            gl16(BHg + boff[q] + k0, BsH + lofs[q]);
            gl16(BLg + boff[q] + k0, BsL + lofs[q]);
        }
    };

    auto frag = [&](const unsigned short* buf, int row, int slot) -> bhalf8 {
        int sp = slot ^ ((row >> 1) & 3);
        return *(const bhalf8*)(buf + row * 32 + sp * 8);
    };

    const int w = tid >> 6, lane = tid & 63;
    const int rw = (w >> 1) * 64, cw = (w & 1) * 64;
    const int lr = lane & 15;
    const int lq = lane >> 4;

    floatx4 acc[4][4];
    const floatx4 fz = {0.f, 0.f, 0.f, 0.f};
    #pragma unroll
    for (int i = 0; i < 4; ++i)
        #pragma unroll
        for (int j = 0; j < 4; ++j) acc[i][j] = fz;

    const int ktiles = K >> 5;   // 48
    stage(0);
    for (int kt = 0; kt < ktiles; ++kt) {
        __syncthreads();
        bhalf8 ah[4], al[4], bh[4], bl[4];
        #pragma unroll
        for (int i = 0; i < 4; ++i) {
            int ra = rw + i * 16 + lr;
            int rb = cw + i * 16 + lr;
            ah[i] = frag(AsH, ra, lq);
            al[i] = frag(AsL, ra, lq);
            bh[i] = frag(BsH, rb, lq);
            bl[i] = frag(BsL, rb, lq);
        }
        __syncthreads();
        if (kt + 1 < ktiles) stage((kt + 1) * 32);
        #pragma unroll
        for (int i = 0; i < 4; ++i)
            #pragma unroll
            for (int j = 0; j < 4; ++j) {
                acc[i][j] = __builtin_amdgcn_mfma_f32_16x16x32_bf16(ah[i], bh[j], acc[i][j], 0, 0, 0);
                acc[i][j] = __builtin_amdgcn_mfma_f32_16x16x32_bf16(ah[i], bl[j], acc[i][j], 0, 0, 0);
                acc[i][j] = __builtin_amdgcn_mfma_f32_16x16x32_bf16(al[i], bh[j], acc[i][j], 0, 0, 0);
            }
    }

    #pragma unroll
    for (int i = 0; i < 4; ++i) {
        #pragma unroll
        for (int j = 0; j < 4; ++j) {
            int gc = n0 + cw + j * 16 + lr;
            #pragma unroll
            for (int rg = 0; rg < 4; ++rg) {
                int gm = m0 + rw + i * 16 + lq * 4 + rg;
                if (dir) gm = (gm & ~(SEQ - 1)) + (SEQ - 1 - (gm & (SEQ - 1)));
                float v = acc[i][j][rg];
                size_t o = (size_t)gm * ldc + coloff + gc;
                unsigned short h, l;
                splitRNE(v, h, l);
                CHo[o] = h; CLo[o] = l;
            }
        }
    }
}

// ---------------- B/C conv + dt/dA (tiny; head-channel conv fused in scan) -
// grid ROWS x 64. tid<32: conv+silu for channel DINNER+tid -> bc[r*32+tid].
// tid in [32,56): dt/dA for head tid-32.
__global__ __launch_bounds__(64) void bcdt_kernel(
    const float* __restrict__ zx, const float* __restrict__ cw,
    const float* __restrict__ cb,
    const float* __restrict__ dt_bias, const float* __restrict__ A_log,
    float* __restrict__ bc, float* __restrict__ dtda)
{
    int r = blockIdx.x;
    int tid = threadIdx.x;
    int t = r & (SEQ - 1);
    int rb = r & ~(SEQ - 1);
    if (tid < 32) {
        int c = DINNER + tid;
        float acc = cb[c];
        #pragma unroll
        for (int k = 0; k < DCONV; ++k) {
            int tt = t - (DCONV - 1) + k;
            if (tt >= 0)
                acc += cw[c * DCONV + k] * zx[(size_t)(rb + tt) * DINPROJ + DINNER + c];
        }
        bc[(size_t)r * 32 + tid] = acc / (1.0f + expf(-acc));
    } else if (tid < 32 + NHEADS) {
        int h = tid - 32;
        float v = zx[(size_t)r * DINPROJ + (DINPROJ - NHEADS) + h] + dt_bias[h];
        float dt = (v > 20.f) ? v : log1pf(expf(v));
        float A = -expf(A_log[h]);
        float2 o = make_float2(dt, expf(dt * A));
        *(float2*)&dtda[(size_t)r * 48 + 2 * h] = o;
    }
}

// ---------------- chunked scan phase A with FUSED depthwise conv ----------
// Each thread owns channel ch = h*64+p across the chunk's 128 rows; the
// causal 4-tap conv+SiLU is computed on the fly with a 3-deep sliding
// window over zx (1 new coalesced load/step — replaces the old xcv load).
// Deletes the conv main kernel and the 100 MB xcv round-trip per dir.
__global__ __launch_bounds__(64) void scan_a(
    const float* __restrict__ zx, const float* __restrict__ bc,
    const float* __restrict__ dtda, const float* __restrict__ Dp,
    const float* __restrict__ cw, const float* __restrict__ cb,
    float* __restrict__ yout, float* __restrict__ S, float* __restrict__ cd)
{
    int blk = blockIdx.x;
    int bh = blk / NCHUNK, c = blk - bh * NCHUNK;
    int b = bh / NHEADS, h = bh - b * NHEADS;
    int p = threadIdx.x;
    int ch = h * HEADDIM + p;

    float xw0 = cw[ch * DCONV + 0], xw1 = cw[ch * DCONV + 1];
    float xw2 = cw[ch * DCONV + 2], xw3 = cw[ch * DCONV + 3];
    float cbv = cb[ch];

    int t0 = c * QCH;
    // sliding window: win0..win2 = x at t0-3, t0-2, t0-1 (0 before seq start)
    float win0 = 0.f, win1 = 0.f, win2 = 0.f;
    {
        int tt = t0 - 3;
        if (tt >= 0) win0 = zx[(size_t)(b * SEQ + tt) * DINPROJ + DINNER + ch];
        tt = t0 - 2;
        if (tt >= 0) win1 = zx[(size_t)(b * SEQ + tt) * DINPROJ + DINNER + ch];
        tt = t0 - 1;
        if (tt >= 0) win2 = zx[(size_t)(b * SEQ + tt) * DINPROJ + DINNER + ch];
    }

    float hs[DSTATE] = {};
    float Dv = Dp[h];
    float cum = 1.f;
    for (int t = t0; t < t0 + QCH; ++t) {
        size_t r = (size_t)b * SEQ + t;
        float xt = zx[r * DINPROJ + DINNER + ch];
        float a = cbv + xw0 * win0 + xw1 * win1 + xw2 * win2 + xw3 * xt;
        win0 = win1; win1 = win2; win2 = xt;
        float x = a / (1.0f + expf(-a));            // conv + silu

        float2 dd = *(const float2*)&dtda[r * 48 + 2 * h];
        float dt = dd.x;
        float dA = dd.y;
        cum *= dA;
        float coef = dt * x;
        const float* bcr = bc + r * 32;
        float y = 0.f;
        #pragma unroll
        for (int n = 0; n < DSTATE; ++n) {
            hs[n] = hs[n] * dA + coef * bcr[n];
            y += hs[n] * bcr[16 + n];
        }
        yout[r * DINPROJ + DINNER + ch] = y + Dv * x;
        if (p == 0) cd[r * NHEADS + h] = cum;
    }
    float* Sp = S + (((size_t)bh * NCHUNK + c) * HEADDIM + p) * DSTATE;
    #pragma unroll
    for (int n = 0; n < DSTATE; ++n) Sp[n] = hs[n];
}

// ---------------- chunked scan, phase B: sequential chunk combine ---------
__global__ __launch_bounds__(64) void scan_b(
    const float* __restrict__ cd, float* __restrict__ S)
{
    int bh = blockIdx.x;
    int b = bh / NHEADS, h = bh - b * NHEADS;
    int p = threadIdx.x;
    float H[DSTATE] = {};
    for (int c = 0; c < NCHUNK; ++c) {
        float* Sp = S + (((size_t)bh * NCHUNK + c) * HEADDIM + p) * DSTATE;
        float P = cd[((size_t)b * SEQ + c * QCH + QCH - 1) * NHEADS + h];
        float s[DSTATE];
        #pragma unroll
        for (int n = 0; n < DSTATE; ++n) s[n] = Sp[n];
        #pragma unroll
        for (int n = 0; n < DSTATE; ++n) Sp[n] = H[n];
        #pragma unroll
        for (int n = 0; n < DSTATE; ++n) H[n] = P * H[n] + s[n];
    }
}

// ---------------- chunked scan, phase C: carry correction -----------------
__global__ __launch_bounds__(64) void scan_c(
    const float* __restrict__ bc, const float* __restrict__ cd,
    const float* __restrict__ S, float* __restrict__ yout)
{
    int blk = blockIdx.x;
    int bh = blk / (NCHUNK - 1), c = blk - bh * (NCHUNK - 1) + 1;
    int b = bh / NHEADS, h = bh - b * NHEADS;
    int p = threadIdx.x;
    const float* Hp = S + (((size_t)bh * NCHUNK + c) * HEADDIM + p) * DSTATE;
    float H[DSTATE];
    #pragma unroll
    for (int n = 0; n < DSTATE; ++n) H[n] = Hp[n];
    int t0 = c * QCH;
    for (int t = t0; t < t0 + QCH; ++t) {
        size_t r = (size_t)b * SEQ + t;
        const float* Cr = bc + r * 32 + 16;
        float dot = 0.f;
        #pragma unroll
        for (int n = 0; n < DSTATE; ++n) dot += H[n] * Cr[n];
        float cum = cd[r * NHEADS + h];
        yout[r * DINPROJ + DINNER + h * HEADDIM + p] += cum * dot;
    }
}

// ---------------- gated RMSNorm -> bf16 hi/lo planes ----------------------
__global__ __launch_bounds__(256) void gnorm_kernel(
    const float* __restrict__ zx, const float* __restrict__ nw,
    unsigned short* __restrict__ H, unsigned short* __restrict__ L)
{
    int r = blockIdx.x;
    const float* zr = zx + (size_t)r * DINPROJ;
    float v[6]; float ss = 0.f;
    #pragma unroll
    for (int i = 0; i < 6; ++i) {
        int c = threadIdx.x + i * 256;
        float z = zr[c];
        float y = zr[DINNER + c];
        float t = y * z / (1.0f + expf(-z));
        v[i] = t; ss += t * t;
    }
    float2 red = blockReduce2(ss, 0.f);
    float sc = rsqrtf(red.x * (1.0f / DINNER) + 1e-5f);
    #pragma unroll
    for (int i = 0; i < 6; ++i) {
        int c = threadIdx.x + i * 256;
        float o = v[i] * sc * nw[c];
        unsigned short h, l;
        splitRNE(o, h, l);
        H[(size_t)r * DINNER + c] = h;
        L[(size_t)r * DINNER + c] = l;
    }
}

extern "C" void kernel_launch(void* const* d_in, const int* in_sizes, int n_in,
                              void* d_out, int out_size, void* d_ws, size_t ws_size,
                              hipStream_t stream)
{
    (void)in_sizes; (void)n_in; (void)out_size; (void)ws_size;
    const float* x     = (const float*)d_in[0];
    const float* ln1w  = (const float*)d_in[1];
    const float* ln1b  = (const float*)d_in[2];
    const float* ln2w  = (const float*)d_in[3];
    const float* ln2b  = (const float*)d_in[4];
    const float* ffnw1 = (const float*)d_in[5];
    const float* ffnb1 = (const float*)d_in[6];
    const float* ffnw2 = (const float*)d_in[7];
    const float* ffnb2 = (const float*)d_in[8];
    const float* p[2][8];
    for (int d = 0; d < 2; ++d)
        for (int i = 0; i < 8; ++i)
            p[d][i] = (const float*)d_in[9 + d * 8 + i];

    // Region map (floats from ws) — identical to r8:
    //   zx   : [0, 25.62M)      — in_proj/scan target per dir; after dir
    //          loop: bi planes lower half, hmH upper half
    //   bi   : [25.62M, 38.21M) — zn0 planes during d1; hmL after
    //   S    : [38.21M, 50.79M) — zn1 planes -> ffn weight planes + ffo
    //   Wbuf : [50.79M, +2.40M) — weight planes; Sbuf/cdbf alias during scans
    float* ws   = (float*)d_ws;
    float* zx   = ws;
    float* bi   = zx + (size_t)ROWS * DINPROJ;
    float* S    = bi + (size_t)ROWS * DINNER;
    float* Wbuf = S  + (size_t)ROWS * DINNER;
    float* bcb  = Wbuf + 2402304;
    float* dtda = bcb + (size_t)ROWS * 32;
    float* Sbuf = Wbuf;                       // alias (dead in_proj weights)
    float* cdbf = Wbuf + (size_t)BATCH * NHEADS * NCHUNK * HEADDIM * DSTATE;

    unsigned short* xnH = (unsigned short*)d_out;              // xn planes in d_out
    unsigned short* xnL = xnH + (size_t)ROWS * DMODEL;
    // zn planes: dir 0 -> bi region, dir 1 -> S
    unsigned short* znH[2] = {(unsigned short*)bi, (unsigned short*)S};
    unsigned short* znL[2] = {znH[0] + (size_t)ROWS * DINNER,
                              znH[1] + (size_t)ROWS * DINNER};
    // bi planes -> zx lower half (zx dead after d1 gnorm)
    unsigned short* biH = (unsigned short*)zx;
    unsigned short* biL = biH + (size_t)ROWS * DINNER;
    // hmid planes: hi -> zx upper half, lo -> bi region (zn0 dead)
    unsigned short* hmH = (unsigned short*)(zx + (size_t)ROWS * DINNER);
    unsigned short* hmL = (unsigned short*)bi;
    float* ffo = S + 4718592;   // after ffn weight-plane region (18.9 MB)

    // 1. ln1: x -> xn bf16 hi/lo planes (in d_out)
    ln_split_kernel<<<ROWS, 256, 0, stream>>>(x, ln1w, ln1b, xnH, xnL);

    for (int d = 0; d < 2; ++d) {
        unsigned short* WH = (unsigned short*)Wbuf;
        unsigned short* WL = WH + (size_t)DINPROJ * DMODEL;
        wconv<<<dim3((DINPROJ + 31) / 32, DMODEL / 32), 256, 0, stream>>>(
            p[d][0], WH, WL, DMODEL, DINPROJ);
        // 2. in_proj: zx = xn(flip if d==1) @ in_w   [8192 x 3128] fp32 out
        gemm3<<<dim3((DINPROJ + 127) / 128, ROWS / 128), 256, 0, stream>>>(
            xnH, xnL, WH, WL, zx, nullptr, nullptr, nullptr,
            ROWS, DINPROJ, DMODEL, DINPROJ, 0, d, 0, 0);
        // 3. B/C conv + dt/dA (tiny; head-channel conv fused into scan_a)
        bcdt_kernel<<<ROWS, 64, 0, stream>>>(
            zx, p[d][1], p[d][2], p[d][3], p[d][4], bcb, dtda);
        // 4. chunked scan (with fused conv+silu) -> y (+D*x) into zx cols
        scan_a<<<BATCH * NHEADS * NCHUNK, 64, 0, stream>>>(
            zx, bcb, dtda, p[d][5], p[d][1], p[d][2], zx, Sbuf, cdbf);
        scan_b<<<BATCH * NHEADS, 64, 0, stream>>>(cdbf, Sbuf);
        scan_c<<<BATCH * NHEADS * (NCHUNK - 1), 64, 0, stream>>>(
            bcb, cdbf, Sbuf, zx);
        // 5. gated RMSNorm -> zn planes (d0 -> bi region, d1 -> S)
        gnorm_kernel<<<ROWS, 256, 0, stream>>>(zx, p[d][6], znH[d], znL[d]);
    }

    // 6. merged out_proj (both directions, one dispatch)
    {
        unsigned short* W0H = (unsigned short*)Wbuf;
        unsigned short* W0L = W0H + (size_t)DMODEL * DINNER;
        unsigned short* W1H = W0L + (size_t)DMODEL * DINNER;
        unsigned short* W1L = W1H + (size_t)DMODEL * DINNER;
        wconv<<<dim3(DMODEL / 32, DINNER / 32), 256, 0, stream>>>(
            p[0][7], W0H, W0L, DINNER, DMODEL);
        wconv<<<dim3(DMODEL / 32, DINNER / 32), 256, 0, stream>>>(
            p[1][7], W1H, W1L, DINNER, DMODEL);
        gemm3d<<<dim3(DMODEL / 128, 2 * ROWS / 128), 256, 0, stream>>>(
            znH[0], znL[0], znH[1], znL[1],
            W0H, W0L, W1H, W1L, biH, biL);
    }

    // 7. ffn1: hmid planes = split(gelu(bi @ w1 + b1))  [8192 x 3072]
    {
        unsigned short* WH = (unsigned short*)S;
        unsigned short* WL = WH + (size_t)DFFN * DINNER;
        wconv<<<dim3(DFFN / 32, DINNER / 32), 256, 0, stream>>>(
            ffnw1, WH, WL, DINNER, DFFN);
        gemm3<<<dim3(DFFN / 128, ROWS / 128), 256, 0, stream>>>(
            biH, biL, WH, WL, nullptr, hmH, hmL, ffnb1,
            ROWS, DFFN, DINNER, DFFN, 0, 0, 0, 1);
    }
    // 8. ffn2: ffo = gelu(hmid @ w2 + b2) [8192 x 768] fp32 (weights in S)
    {
        unsigned short* WH = (unsigned short*)S;
        unsigned short* WL = WH + (size_t)DMODEL * DFFN;
        wconv<<<dim3(DMODEL / 32, DFFN / 32), 256, 0, stream>>>(
            ffnw2, WH, WL, DFFN, DMODEL);
        gemm3<<<dim3(DMODEL / 128, ROWS / 128), 256, 0, stream>>>(
            hmH, hmL, WH, WL, ffo, nullptr, nullptr, ffnb2,
            ROWS, DMODEL, DFFN, DMODEL, 0, 0, 0, 1);
    }
    // 9. final layernorm(x + ffo) -> out (xn planes dead)
    ln_kernel<<<ROWS, 256, 0, stream>>>(x, ffo, ln2w, ln2b, (float*)d_out);
}